// Round 2
// baseline (2923.175 us; speedup 1.0000x reference)
//
#include <hip/hip_runtime.h>
#include <stdint.h>

// ---------------------------------------------------------------------------
// SimpleEdgeBlock: two FullyConnectedTensorProducts (64x0e+64x1o)^2 -> same,
// summed. One bf16 MFMA GEMM:
//   rows = 4 tiles per 32-edge group (out0, out1_i)   M = 4E
//   cols = w                                          N = 64 (split across waves)
//   K    = 16384 = pair(2) x half(2) x v(64) x u(64)
// B (weights, scales folded) prepacked bf16 in d_ws, PRE-SWIZZLED to the
// staging order so the K-loop stages each 8 KB slab with coalesced
// global_load_lds (width 16). A (z = x[u]*y[v]) synthesized in registers:
// x register-cached bf16, y one ds_read_b64 per wave per slab.
// Block: 256 thr = 4 waves = (edge-half we) x (n-half wn); 64 edges/block.
// LDS 48 KB -> 3 blocks/CU; VGPR target <=168 -> 12 waves/CU.
// ---------------------------------------------------------------------------

typedef __attribute__((ext_vector_type(8))) short short8;   // 8 x bf16
typedef __attribute__((ext_vector_type(16))) float f32x16;  // MFMA 32x32 acc
typedef unsigned short u16;
typedef unsigned int u32;

#define ETOT 100000

__device__ __forceinline__ unsigned pk2(float lo, float hi) {
  // pack hi16(lo), hi16(hi) -> one dword (bf16 truncation; bias cancels in sums)
  return __builtin_amdgcn_perm(__builtin_bit_cast(unsigned, hi),
                               __builtin_bit_cast(unsigned, lo), 0x07060302u);
}
__device__ __forceinline__ float bf2f(u16 s) {
  return __builtin_bit_cast(float, ((unsigned)s) << 16);
}
__device__ __forceinline__ void unpk8(short8 s, float f[8]) {
  uint4 u = __builtin_bit_cast(uint4, s);
  unsigned a[4] = {u.x, u.y, u.z, u.w};
#pragma unroll
  for (int jj = 0; jj < 4; ++jj) {
    f[2 * jj]     = __builtin_bit_cast(float, a[jj] << 16);
    f[2 * jj + 1] = __builtin_bit_cast(float, a[jj] & 0xffff0000u);
  }
}
__device__ __forceinline__ short8 scalepack(const float f[8], float ysc) {
  unsigned p0 = pk2(f[0] * ysc, f[1] * ysc);
  unsigned p1 = pk2(f[2] * ysc, f[3] * ysc);
  unsigned p2 = pk2(f[4] * ysc, f[5] * ysc);
  unsigned p3 = pk2(f[6] * ysc, f[7] * ysc);
  uint4 r = make_uint4(p0, p1, p2, p3);
  return __builtin_bit_cast(short8, r);
}
__device__ __forceinline__ short8 pack8(const float f[8]) {
  unsigned p0 = pk2(f[0], f[1]);
  unsigned p1 = pk2(f[2], f[3]);
  unsigned p2 = pk2(f[4], f[5]);
  unsigned p3 = pk2(f[6], f[7]);
  uint4 r = make_uint4(p0, p1, p2, p3);
  return __builtin_bit_cast(short8, r);
}

// ---------------------------------------------------------------------------
// Prep: W (fp32 [u][v][w]) -> B bf16 in STAGING-SWIZZLED order:
//   idx = [t(1)][p(1)][s(8)][oct(2)][w(6)][j(3)],  k_in_pair = s*32 + oct*8 + j
//   k decodes as: half = k>>12, v = (k>>6)&63, u = k&63
//   t=0: half0 = a0*W_000,       half1 = a0/sqrt3 * W_110
//   t=1: half0 = a0/sqrt3*W_011, half1 = a0/sqrt3 * W_101
// ---------------------------------------------------------------------------
__global__ void prep_B(const float* __restrict__ W10, const float* __restrict__ W11,
                       const float* __restrict__ W12, const float* __restrict__ W13,
                       const float* __restrict__ W20, const float* __restrict__ W21,
                       const float* __restrict__ W22, const float* __restrict__ W23,
                       u16* __restrict__ B) {
  int idx = blockIdx.x * 256 + threadIdx.x;  // 2*2*256*2048 = 2097152 total
  int j = idx & 7;
  int w = (idx >> 3) & 63;
  int oct = (idx >> 9) & 3;
  int s = (idx >> 11) & 255;
  int p = (idx >> 19) & 1;
  int t = (idx >> 20) & 1;
  int k = s * 32 + oct * 8 + j;
  int half = k >> 12;
  int v = (k >> 6) & 63;
  int u = k & 63;
  const float a0 = 0.011048543456039806f;       // 1/sqrt(2*64*64)
  const float a0s3 = a0 * 0.5773502691896258f;  // a0/sqrt(3)
  const float* Wsrc;
  float scale;
  if (t == 0) {
    Wsrc = half ? (p ? W21 : W11) : (p ? W20 : W10);
    scale = half ? a0s3 : a0;
  } else {
    Wsrc = half ? (p ? W23 : W13) : (p ? W22 : W12);
    scale = a0s3;
  }
  float val = Wsrc[u * 4096 + v * 64 + w] * scale;
  unsigned ub = __builtin_bit_cast(unsigned, val);
  ub += 0x7fffu + ((ub >> 16) & 1u);  // RTNE
  B[idx] = (u16)(ub >> 16);
}

// ---------------------------------------------------------------------------
// Main kernel.
// ---------------------------------------------------------------------------
__global__ __launch_bounds__(256, 3)
void tp_main(const float* __restrict__ e1x, const float* __restrict__ e1y,
             const float* __restrict__ e2x, const float* __restrict__ e2y,
             const u16* __restrict__ B, float* __restrict__ out) {
  __shared__ u16 ylds[64 * 64 * 4];  // [v][row][ch]  32 KB
  __shared__ u16 blds[2][4096];      // [buf][t][oct][w][j]  2 x 8 KB

  const int tid = threadIdx.x;
  const int wave = tid >> 6;
  const int lane = tid & 63;
  const int m = lane & 31;   // MFMA row/col within 32-tile
  const int hw = lane >> 5;  // half-wave -> k-octet select
  const int we = wave & 1;   // edge-half
  const int wn = wave >> 1;  // n-half
  const int be0 = blockIdx.x * 64;
  const int e0 = be0 + we * 32;
  const bool active = (e0 < ETOT);
  const int e = e0 + m;

  f32x16 acc[4] = {};  // t-tiles (out0, out1_0, out1_1, out1_2), n = wn*32+m
  short8 xc[4][4];     // x cache: [ch][u-quarter]; ch: x0, x1_0, x1_1, x1_2

  const int lfrag = (hw * 64 + wn * 32 + m) * 8;  // lane part of blds elem idx
  const int yrow = (we * 32 + m) * 4;             // lane part of ylds elem idx

  // async stage one 8 KB slab (both types) for pair p, slab s -> blds[dstbuf]
  auto stage = [&](int p, int s, int dstbuf) {
#pragma unroll
    for (int q = 0; q < 2; ++q) {  // q == t (256 threads)
      size_t g = ((size_t)((q * 2 + p) * 256 + s)) * 2048 + (size_t)tid * 8;
      int flat = q * 256 + tid;
      __builtin_amdgcn_global_load_lds(
          (const __attribute__((address_space(1))) u32*)(B + g),
          (__attribute__((address_space(3))) u32*)(&blds[dstbuf][flat * 8]),
          16, 0, 0);
    }
  };

  int buf = 0;
#pragma unroll 1
  for (int p = 0; p < 2; ++p) {
    const float* X = p ? e2x : e1x;
    const float* Y = p ? e2y : e1y;
    __syncthreads();  // previous pair's ylds reads complete

    // ---- stage y (block's 64 edges) into ylds[v][row][ch], bf16 ----
#pragma unroll 4
    for (int n = 0; n < 16; ++n) {
      int flat4 = n * 256 + tid;  // coalesced float4 index
      int r = flat4 >> 6;
      int c4 = flat4 & 63;
      if (be0 + r < ETOT) {
        float4 v4 = *(const float4*)(Y + (size_t)(be0 + r) * 256 + c4 * 4);
        float vv[4] = {v4.x, v4.y, v4.z, v4.w};
#pragma unroll
        for (int kk = 0; kk < 4; ++kk) {
          int d = c4 * 4 + kk;
          int ch, vi;
          if (d < 64) { ch = 0; vi = d; }
          else { int dd = d - 64; ch = 1 + dd % 3; vi = dd / 3; }
          ylds[vi * 256 + r * 4 + ch] =
              (u16)(__builtin_bit_cast(unsigned, vv[kk]) >> 16);
        }
      }
    }

    // ---- gather x into registers (bf16 packed), per lane: its u-slices ----
    if (active) {
#pragma unroll
      for (int q = 0; q < 4; ++q) {  // u = q*16 + hw*8 + j
        const float* px = X + (size_t)e * 256 + q * 16 + hw * 8;
        float4 a4 = *(const float4*)px;
        float4 b4 = *(const float4*)(px + 4);
        float f[8] = {a4.x, a4.y, a4.z, a4.w, b4.x, b4.y, b4.z, b4.w};
        xc[0][q] = pack8(f);
      }
#pragma unroll
      for (int i = 0; i < 3; ++i) {
        const float* px = X + (size_t)e * 256 + 64 + i;
#pragma unroll
        for (int q = 0; q < 4; ++q) {
          float f[8];
#pragma unroll
          for (int j = 0; j < 8; ++j) f[j] = px[(q * 16 + hw * 8 + j) * 3];
          xc[1 + i][q] = pack8(f);
        }
      }
    }

    stage(p, 0, buf);
    __syncthreads();

#pragma unroll 1
    for (int s = 0; s < 256; ++s) {  // 256 slabs x 32 k = 8192 k per pair
      if (s < 255) stage(p, s + 1, buf ^ 1);
      if (active) {
        const u16* bb = blds[buf];
        const int half = s >> 7;       // wave-uniform
        const int lv = (s >> 1) & 63;  // v for this slab
        const int uh = s & 1;          // u-half
        // y scalars for this v, all 4 channels, one b64 read
        ushort4 y4 = *(const ushort4*)&ylds[lv * 256 + yrow];
        float ys0 = bf2f(y4.x), ys1 = bf2f(y4.y);
        float ys2 = bf2f(y4.z), ys3 = bf2f(y4.w);
#pragma unroll
        for (int ksub = 0; ksub < 2; ++ksub) {
          int qx = uh * 2 + ksub;  // u-quarter
          short8 bf0 = *(const short8*)&bb[ksub * 1024 + lfrag];         // t=0
          short8 bf1 = *(const short8*)&bb[2048 + ksub * 1024 + lfrag];  // t=1
          short8 af[4];
          if (half == 0) {  // z = x0[u]*y_b[v]
            float xf[8];
            unpk8(xc[0][qx], xf);
            af[0] = scalepack(xf, ys0);
            af[1] = scalepack(xf, ys1);
            af[2] = scalepack(xf, ys2);
            af[3] = scalepack(xf, ys3);
          } else {  // t0: z110 = sum_i x1_i*y1_i;  t_i: x1_i*y0
            float x0f[8], x1f[8], x2f[8];
            unpk8(xc[1][qx], x0f);
            unpk8(xc[2][qx], x1f);
            unpk8(xc[3][qx], x2f);
            float z[8];
#pragma unroll
            for (int j = 0; j < 8; ++j)
              z[j] = x0f[j] * ys1 + x1f[j] * ys2 + x2f[j] * ys3;
            af[0] = pack8(z);
            af[1] = scalepack(x0f, ys0);
            af[2] = scalepack(x1f, ys0);
            af[3] = scalepack(x2f, ys0);
          }
          acc[0] = __builtin_amdgcn_mfma_f32_32x32x16_bf16(af[0], bf0, acc[0], 0, 0, 0);
          acc[1] = __builtin_amdgcn_mfma_f32_32x32x16_bf16(af[1], bf1, acc[1], 0, 0, 0);
          acc[2] = __builtin_amdgcn_mfma_f32_32x32x16_bf16(af[2], bf1, acc[2], 0, 0, 0);
          acc[3] = __builtin_amdgcn_mfma_f32_32x32x16_bf16(af[3], bf1, acc[3], 0, 0, 0);
        }
      }
      __syncthreads();
      buf ^= 1;
    }
  }

  // ---- epilogue: C/D layout col=lane&31, row=(reg&3)+8*(reg>>2)+4*hw ----
  if (active) {
    const int n = wn * 32 + m;  // w index
#pragma unroll
    for (int t = 0; t < 4; ++t) {
      f32x16 c = acc[t];
#pragma unroll
      for (int r = 0; r < 16; ++r) {
        int row = (r & 3) + 8 * (r >> 2) + 4 * hw;
        int ee = e0 + row;
        size_t off;
        if (t == 0) off = (size_t)ee * 256 + n;                     // out0[w]
        else        off = (size_t)ee * 256 + 64 + n * 3 + (t - 1);  // out1[w][i]
        out[off] = c[r];
      }
    }
  }
}

extern "C" void kernel_launch(void* const* d_in, const int* in_sizes, int n_in,
                              void* d_out, int out_size, void* d_ws, size_t ws_size,
                              hipStream_t stream) {
  const float* e1x = (const float*)d_in[0];
  const float* e1y = (const float*)d_in[1];
  const float* e2x = (const float*)d_in[2];
  const float* e2y = (const float*)d_in[3];
  const size_t bElems = (size_t)2 * 64 * 16384;  // 2 Mi elems bf16 = 4 MiB
  if (ws_size < bElems * sizeof(u16)) return;
  u16* B = (u16*)d_ws;
  prep_B<<<8192, 256, 0, stream>>>(
      (const float*)d_in[4], (const float*)d_in[5], (const float*)d_in[6],
      (const float*)d_in[7], (const float*)d_in[8], (const float*)d_in[9],
      (const float*)d_in[10], (const float*)d_in[11], B);
  tp_main<<<(ETOT + 63) / 64, 256, 0, stream>>>(e1x, e1y, e2x, e2y, B,
                                                (float*)d_out);
}